// Round 1
// baseline (1931.514 us; speedup 1.0000x reference)
//
#include <hip/hip_runtime.h>

// ResidualSimVQ eval forward.
// Key algebra: implicit_c = CB_c @ Wn^T + b  (rank CD=8) =>
//   res . implicit_c = sum_k cb_ck * p_k + res.b,  p = res @ Wn  (8 dots/row)
// so the 1024-way argmin needs only p (res.b is code-independent).
// rotate_to(res, zq) output is in span{res, zq}:  rot = A*res + C*zq with
// wave-uniform A, C from {||res||^2, ||zq||^2, res.zq}.
// Everything on the argmin/residual path is f64 (flips cascade; codes absmax
// threshold tolerates zero flipped indices). Scoring uses an f32 fast path
// with a guaranteed f64 fallback when the top-2 gap < 0.03 (f32 error << that).

#define NB  16
#define DD  512
#define TT  2048
#define NCB 9
#define CS  1024
#define CD  8

#define WS_WN_OFF 4096                            // f64 Wn, k-major: [i][k][d]
#define WS_Q_OFF  (WS_WN_OFF + (size_t)NCB*DD*CD*8)   // f64 ||implicit||^2: [i][c]
#define WS_QF_OFF (WS_Q_OFF  + (size_t)NCB*CS*8)      // f32 copy of q

__global__ void k_wn(const float* __restrict__ V, const float* __restrict__ g,
                     double* __restrict__ wn) {
  int gid = blockIdx.x * 256 + threadIdx.x;
  if (gid >= NCB * DD) return;
  int i = gid / DD, d = gid % DD;
  const float* vp = V + (size_t)gid * CD;
  double v[CD], s = 0.0;
#pragma unroll
  for (int k = 0; k < CD; k++) { v[k] = (double)vp[k]; s = fma(v[k], v[k], s); }
  double den = fmax(sqrt(s), 1e-12);
  double gg = (double)g[gid];
#pragma unroll
  for (int k = 0; k < CD; k++)
    wn[((size_t)i * CD + k) * DD + d] = gg * v[k] / den;   // k-major store
}

__global__ void k_q(const float* __restrict__ CBp, const float* __restrict__ bp,
                    const double* __restrict__ wn,
                    double* __restrict__ q, float* __restrict__ qf) {
  int wid = blockIdx.x * 4 + (threadIdx.x >> 6);
  int lane = threadIdx.x & 63;
  int i = wid / CS, c = wid % CS;
  const float* cb = CBp + (size_t)(i * CS + c) * CD;
  double cbv[CD];
#pragma unroll
  for (int k = 0; k < CD; k++) cbv[k] = (double)cb[k];
  const double* wnp = wn + (size_t)i * DD * CD;
  const float* bb = bp + (size_t)i * DD;
  double acc = 0.0;
#pragma unroll
  for (int j = 0; j < 8; j++) {
    int d = j * 64 + lane;
    double imp = (double)bb[d];
#pragma unroll
    for (int k = 0; k < CD; k++) imp = fma(cbv[k], wnp[(size_t)k * DD + d], imp);
    acc = fma(imp, imp, acc);
  }
#pragma unroll
  for (int o = 32; o; o >>= 1) acc += __shfl_xor(acc, o, 64);
  if (lane == 0) { q[wid] = acc; qf[wid] = (float)acc; }
}

__launch_bounds__(256)
__global__ void k_main(const float* __restrict__ z, const float* __restrict__ bvec,
                       const float* __restrict__ CBp,
                       const double* __restrict__ wn, const double* __restrict__ qtab,
                       const float* __restrict__ qftab,
                       float* __restrict__ out_zq, float* __restrict__ out_codes,
                       double* __restrict__ accp) {
  __shared__ double wnl[CD * DD];   // k-major: wnl[k*512 + d]
  __shared__ float tile[DD * 5];    // transpose buffer, pad 5 (gcd(5,32)=1)

  const int tid = threadIdx.x, lane = tid & 63, w = tid >> 6;
  const int bb = blockIdx.x >> 9, tg = blockIdx.x & 511;
  const int t0 = tg * 4, t = t0 + w;

  // ---- load z[b, :, t0..t0+3] via LDS transpose (16B coalesced chunks) ----
#pragma unroll
  for (int r = 0; r < 2; r++) {
    int d = tid + r * 256;
    const float4 v = *(const float4*)(z + ((size_t)bb * DD + d) * TT + t0);
    tile[d * 5 + 0] = v.x; tile[d * 5 + 1] = v.y;
    tile[d * 5 + 2] = v.z; tile[d * 5 + 3] = v.w;
  }
  __syncthreads();

  double res[8], zqs[8];
#pragma unroll
  for (int j = 0; j < 8; j++) {
    res[j] = (double)tile[(j * 64 + lane) * 5 + w];   // lane owns d = j*64+lane
    zqs[j] = 0.0;
  }
  double commit = 0.0;

  for (int i = 0; i < NCB; i++) {
    __syncthreads();
#pragma unroll
    for (int m = 0; m < 16; m++)
      wnl[tid + m * 256] = wn[(size_t)i * (DD * CD) + tid + m * 256];
    __syncthreads();

    // ---- p = res @ Wn (f64), plus ||res||^2 ----
    double ns2 = 0.0, p[8];
#pragma unroll
    for (int k = 0; k < 8; k++) p[k] = 0.0;
#pragma unroll
    for (int j = 0; j < 8; j++) {
      int d = j * 64 + lane;
      ns2 = fma(res[j], res[j], ns2);
#pragma unroll
      for (int k = 0; k < 8; k++) p[k] = fma(res[j], wnl[k * DD + d], p[k]);
    }
#pragma unroll
    for (int o = 32; o; o >>= 1) ns2 += __shfl_xor(ns2, o, 64);
#pragma unroll
    for (int k = 0; k < 8; k++) {
#pragma unroll
      for (int o = 32; o; o >>= 1) p[k] += __shfl_xor(p[k], o, 64);
      p[k] = -2.0 * p[k];            // p now holds m2p (f64)
    }
    float m2pf[8];
#pragma unroll
    for (int k = 0; k < 8; k++) m2pf[k] = (float)p[k];

    // ---- argmin: f32 fast path with top-2 gap tracking ----
    const float* cbbase = CBp + (size_t)i * CS * CD;
    float s1 = 3.4e38f, s2 = 3.4e38f; int c1 = 0;
#pragma unroll
    for (int m = 0; m < 16; m++) {
      int c = m * 64 + lane;
      const float4 c0 = *(const float4*)(cbbase + (size_t)c * CD);
      const float4 cx = *(const float4*)(cbbase + (size_t)c * CD + 4);
      float s = qftab[i * CS + c];
      s = fmaf(c0.x, m2pf[0], s); s = fmaf(c0.y, m2pf[1], s);
      s = fmaf(c0.z, m2pf[2], s); s = fmaf(c0.w, m2pf[3], s);
      s = fmaf(cx.x, m2pf[4], s); s = fmaf(cx.y, m2pf[5], s);
      s = fmaf(cx.z, m2pf[6], s); s = fmaf(cx.w, m2pf[7], s);
      if (s < s1) { s2 = s1; s1 = s; c1 = c; } else { s2 = fminf(s2, s); }
    }
#pragma unroll
    for (int o = 32; o; o >>= 1) {   // symmetric top-2 merge -> all lanes agree
      float os1 = __shfl_xor(s1, o, 64);
      int   oc1 = __shfl_xor(c1, o, 64);
      float os2 = __shfl_xor(s2, o, 64);
      float hi = fmaxf(s1, os1);
      s2 = fminf(fminf(s2, os2), hi);
      if (os1 < s1 || (os1 == s1 && oc1 < c1)) { s1 = os1; c1 = oc1; }
    }
    if (s2 - s1 < 0.03f) {           // wave-uniform; rare: exact f64 re-score
      double bs = 1e300; int bc = 0;
#pragma unroll 4
      for (int m = 0; m < 16; m++) {
        int c = m * 64 + lane;
        const float* cb = cbbase + (size_t)c * CD;
        double s = qtab[i * CS + c];
#pragma unroll
        for (int k = 0; k < 8; k++) s = fma((double)cb[k], p[k], s);
        if (s < bs) { bs = s; bc = c; }
      }
#pragma unroll
      for (int o = 32; o; o >>= 1) {
        double obs = __shfl_xor(bs, o, 64);
        int    obc = __shfl_xor(bc, o, 64);
        if (obs < bs || (obs == bs && obc < bc)) { bs = obs; bc = obc; }
      }
      c1 = bc;
    }

    // ---- gather zq = implicit[c1] (recompute from rank-8), dots ----
    const float* cbr = cbbase + (size_t)c1 * CD;
    double cbv[8];
#pragma unroll
    for (int k = 0; k < 8; k++) cbv[k] = (double)cbr[k];
    double zq[8], nt2 = 0.0, pz = 0.0;
#pragma unroll
    for (int j = 0; j < 8; j++) {
      int d = j * 64 + lane;
      double imp = (double)bvec[(size_t)i * DD + d];
#pragma unroll
      for (int k = 0; k < 8; k++) imp = fma(cbv[k], wnl[k * DD + d], imp);
      zq[j] = imp;
      nt2 = fma(imp, imp, nt2);
      pz  = fma(res[j], imp, pz);
      double df = res[j] - imp;
      commit = fma(df, df, commit);
    }
#pragma unroll
    for (int o = 32; o; o >>= 1) { nt2 += __shfl_xor(nt2, o, 64); pz += __shfl_xor(pz, o, 64); }

    // ---- rotation trick as rot = A*res + C*zq ----
    double ns = sqrt(ns2), nt = sqrt(nt2);
    double dns = fmax(ns, 1e-6), dnt = fmax(nt, 1e-6);
    double rns = 1.0 / dns, rnt = 1.0 / dnt;
    double uq = pz * rns * rnt;
    double wn2v = ns2 * rns * rns + 2.0 * uq + nt2 * rnt * rnt;
    double rdwn = 1.0 / fmax(sqrt(wn2v), 1e-6);
    double eu = ns2 * rns;
    double ew = (ns2 * rns + pz * rnt) * rdwn;
    double scale = nt * rns;
    double A = scale * (1.0 - 2.0 * ew * rdwn * rns);
    double C = scale * rnt * 2.0 * (eu - ew * rdwn);
#pragma unroll
    for (int j = 0; j < 8; j++) {
      double rot = A * res[j] + C * zq[j];
      zqs[j] += rot;
      res[j] -= rot;
    }
    if (lane == 0)
      out_codes[((size_t)bb * NCB + i) * TT + t] = (float)c1;
  }

  // ---- commit loss: per-lane accumulated; one f64 atomic per wave ----
#pragma unroll
  for (int o = 32; o; o >>= 1) commit += __shfl_xor(commit, o, 64);
  if (lane == 0) atomicAdd(accp, commit);

  // ---- store z_q (transpose back via LDS) ----
  __syncthreads();
#pragma unroll
  for (int j = 0; j < 8; j++) tile[(j * 64 + lane) * 5 + w] = (float)zqs[j];
  __syncthreads();
#pragma unroll
  for (int r = 0; r < 2; r++) {
    int d = tid + r * 256;
    float4 v;
    v.x = tile[d * 5 + 0]; v.y = tile[d * 5 + 1];
    v.z = tile[d * 5 + 2]; v.w = tile[d * 5 + 3];
    *(float4*)(out_zq + ((size_t)bb * DD + d) * TT + t0) = v;
  }
}

__global__ void k_fin(const double* __restrict__ accp, float* __restrict__ outc) {
  // sum_i 1.25 * mean_i ; all stages share the same 1/(B*T*D) scale
  outc[0] = (float)(accp[0] * 1.25 / (double)((size_t)NB * TT * DD));
}

extern "C" void kernel_launch(void* const* d_in, const int* in_sizes, int n_in,
                              void* d_out, int out_size, void* d_ws, size_t ws_size,
                              hipStream_t stream) {
  const float* z  = (const float*)d_in[0];
  const float* V  = (const float*)d_in[1];
  const float* g  = (const float*)d_in[2];
  const float* b  = (const float*)d_in[3];
  const float* CB = (const float*)d_in[4];
  float* out = (float*)d_out;

  double* acc = (double*)d_ws;
  double* wn  = (double*)((char*)d_ws + WS_WN_OFF);
  double* q   = (double*)((char*)d_ws + WS_Q_OFF);
  float*  qf  = (float*)((char*)d_ws + WS_QF_OFF);

  hipMemsetAsync(d_ws, 0, 64, stream);  // zero commit accumulator each call
  hipLaunchKernelGGL(k_wn, dim3((NCB * DD) / 256), dim3(256), 0, stream, V, g, wn);
  hipLaunchKernelGGL(k_q, dim3((NCB * CS) / 4), dim3(256), 0, stream, CB, b, wn, q, qf);
  hipLaunchKernelGGL(k_main, dim3((NB * TT) / 4), dim3(256), 0, stream,
                     z, b, CB, wn, q, qf,
                     out, out + (size_t)NB * DD * TT, acc);
  hipLaunchKernelGGL(k_fin, dim3(1), dim3(1), 0, stream,
                     acc, out + (size_t)NB * DD * TT + (size_t)NB * NCB * TT);
}

// Round 2
// 1205.555 us; speedup vs baseline: 1.6022x; 1.6022x over previous
//
#include <hip/hip_runtime.h>

// ResidualSimVQ eval forward — R2: amortized/ILP restructure.
// implicit_c = CB_c @ Wn^T + b (rank 8) => argmin needs only p = res@[Wn|b].
// rot = A*res + C*zq with wave-uniform scalars; res' = (1-A)res - C*zq;
// ns2 tracked by recurrence, nt2 from qtab, pz = pb + cb.p  (no elementwise
// reductions except the p-GEMM itself).
// f32 scoring + gap-triggered exact-f64 fallback (identical to passing R1).

#define NB  16
#define DD  512
#define TT  2048
#define NCB 9
#define CS  1024
#define CD  8
#define KK  9   // CD + 1: row 8 of the table is the bias b

#define WS_WN_OFF 4096
#define WS_Q_OFF  (WS_WN_OFF + (size_t)NCB*KK*DD*8)
#define WS_QF_OFF (WS_Q_OFF  + (size_t)NCB*CS*8)

__global__ void k_wn(const float* __restrict__ V, const float* __restrict__ g,
                     const float* __restrict__ bp, double* __restrict__ wn) {
  int gid = blockIdx.x * 256 + threadIdx.x;
  if (gid >= NCB * DD) return;
  int i = gid / DD, d = gid % DD;
  const float* vp = V + (size_t)gid * CD;
  double v[CD], s = 0.0;
#pragma unroll
  for (int k = 0; k < CD; k++) { v[k] = (double)vp[k]; s = fma(v[k], v[k], s); }
  double den = fmax(sqrt(s), 1e-12);
  double gg = (double)g[gid];
#pragma unroll
  for (int k = 0; k < CD; k++)
    wn[((size_t)i * KK + k) * DD + d] = gg * v[k] / den;
  wn[((size_t)i * KK + CD) * DD + d] = (double)bp[gid];   // bias row
}

__global__ void k_q(const float* __restrict__ CBp, const float* __restrict__ bp,
                    const double* __restrict__ wn,
                    double* __restrict__ q, float* __restrict__ qf) {
  int wid = blockIdx.x * 4 + (threadIdx.x >> 6);
  int lane = threadIdx.x & 63;
  int i = wid / CS, c = wid % CS;
  const float* cb = CBp + (size_t)(i * CS + c) * CD;
  double cbv[CD];
#pragma unroll
  for (int k = 0; k < CD; k++) cbv[k] = (double)cb[k];
  const double* wnp = wn + (size_t)i * KK * DD;
  const float* bb = bp + (size_t)i * DD;
  double acc = 0.0;
#pragma unroll
  for (int j = 0; j < 8; j++) {
    int d = j * 64 + lane;
    double imp = (double)bb[d];
#pragma unroll
    for (int k = 0; k < CD; k++) imp = fma(cbv[k], wnp[(size_t)k * DD + d], imp);
    acc = fma(imp, imp, acc);
  }
#pragma unroll
  for (int o = 32; o; o >>= 1) acc += __shfl_xor(acc, o, 64);
  if (lane == 0) { q[wid] = acc; qf[wid] = (float)acc; }
}

__launch_bounds__(256, 3)
__global__ void k_main(const float* __restrict__ z, const float* __restrict__ CBp,
                       const double* __restrict__ wn, const double* __restrict__ qtab,
                       const float* __restrict__ qftab,
                       float* __restrict__ out_zq, float* __restrict__ out_codes,
                       double* __restrict__ accp) {
  __shared__ __align__(16) double smem_d[KK * DD];   // 36864 B
  double* wnl = smem_d;
  float*  tile = (float*)smem_d;                     // needs 512*17*4 = 34816 B

  const int tid = threadIdx.x, lane = tid & 63, w = tid >> 6;
  const int bb = blockIdx.x >> 7, tg = blockIdx.x & 127;
  const int t0 = tg * 16;
  const float* zb = z + (size_t)bb * DD * TT + t0;

  // ---- stage z[b, :, t0:t0+16] coalesced (float4 over t), transpose in LDS --
#pragma unroll
  for (int m = 0; m < 8; m++) {
    int F = tid + m * 256, d = F >> 2, qq = F & 3;
    const float4 v = *(const float4*)(zb + (size_t)d * TT + qq * 4);
    tile[d * 17 + qq * 4 + 0] = v.x; tile[d * 17 + qq * 4 + 1] = v.y;
    tile[d * 17 + qq * 4 + 2] = v.z; tile[d * 17 + qq * 4 + 3] = v.w;
  }
  __syncthreads();

  double res[4][8], ns2[4];
#pragma unroll
  for (int r = 0; r < 4; r++) {
    double s = 0.0;
#pragma unroll
    for (int j = 0; j < 8; j++) {
      res[r][j] = (double)tile[(j * 64 + lane) * 17 + (w * 4 + r)];
      s = fma(res[r][j], res[r][j], s);
    }
    ns2[r] = s;
  }
#pragma unroll
  for (int o = 32; o; o >>= 1)
#pragma unroll
    for (int r = 0; r < 4; r++) ns2[r] += __shfl_xor(ns2[r], o, 64);
  __syncthreads();

  double commit = 0.0;

  for (int i = 0; i < NCB; i++) {
    // ---- stage [Wn | b] (f64, k-major) ----
#pragma unroll
    for (int m = 0; m < 18; m++)
      wnl[tid + m * 256] = wn[(size_t)i * (KK * DD) + tid + m * 256];
    __syncthreads();

    const float* cbbase = CBp + (size_t)i * CS * CD;
    const float* qfb = qftab + i * CS;
    int    c1i[4];
    double pzv[4], nt2v[4];

#pragma unroll
    for (int pr = 0; pr < 2; pr++) {
      // ---- phase 1: p[u][k] = res . [Wn|b]  (2 rows interleaved) ----
      double p[2][KK];
#pragma unroll
      for (int u = 0; u < 2; u++)
#pragma unroll
        for (int k = 0; k < KK; k++) p[u][k] = 0.0;
#pragma unroll
      for (int j = 0; j < 8; j++) {
        int d = j * 64 + lane;
        double wv[KK];
#pragma unroll
        for (int k = 0; k < KK; k++) wv[k] = wnl[k * DD + d];
#pragma unroll
        for (int u = 0; u < 2; u++) {
          double rv = res[2 * pr + u][j];
#pragma unroll
          for (int k = 0; k < KK; k++) p[u][k] = fma(rv, wv[k], p[u][k]);
        }
      }
#pragma unroll
      for (int o = 32; o; o >>= 1)
#pragma unroll
        for (int u = 0; u < 2; u++)
#pragma unroll
          for (int k = 0; k < KK; k++) p[u][k] += __shfl_xor(p[u][k], o, 64);

      // ---- phase 2: f32 argmin with top-2 gap tracking (2 rows) ----
      float m2[2][8];
#pragma unroll
      for (int u = 0; u < 2; u++)
#pragma unroll
        for (int k = 0; k < 8; k++) m2[u][k] = (float)(-2.0 * p[u][k]);
      float s1[2] = {3.4e38f, 3.4e38f}, s2[2] = {3.4e38f, 3.4e38f};
      int   c1[2] = {0, 0};
#pragma unroll 4
      for (int m = 0; m < 16; m++) {
        int c = m * 64 + lane;
        const float4 c0 = *(const float4*)(cbbase + (size_t)c * CD);
        const float4 cx = *(const float4*)(cbbase + (size_t)c * CD + 4);
        float qv = qfb[c];
#pragma unroll
        for (int u = 0; u < 2; u++) {
          float s = qv;
          s = fmaf(c0.x, m2[u][0], s); s = fmaf(c0.y, m2[u][1], s);
          s = fmaf(c0.z, m2[u][2], s); s = fmaf(c0.w, m2[u][3], s);
          s = fmaf(cx.x, m2[u][4], s); s = fmaf(cx.y, m2[u][5], s);
          s = fmaf(cx.z, m2[u][6], s); s = fmaf(cx.w, m2[u][7], s);
          if (s < s1[u]) { s2[u] = s1[u]; s1[u] = s; c1[u] = c; }
          else           { s2[u] = fminf(s2[u], s); }
        }
      }
#pragma unroll
      for (int o = 32; o; o >>= 1) {
#pragma unroll
        for (int u = 0; u < 2; u++) {
          float os1 = __shfl_xor(s1[u], o, 64);
          int   oc1 = __shfl_xor(c1[u], o, 64);
          float os2 = __shfl_xor(s2[u], o, 64);
          float hi = fmaxf(s1[u], os1);
          s2[u] = fminf(fminf(s2[u], os2), hi);
          if (os1 < s1[u] || (os1 == s1[u] && oc1 < c1[u])) { s1[u] = os1; c1[u] = oc1; }
        }
      }
#pragma unroll
      for (int u = 0; u < 2; u++) {
        if (s2[u] - s1[u] < 0.03f) {      // wave-uniform, rare: exact f64
          double pm2[8];
#pragma unroll
          for (int k = 0; k < 8; k++) pm2[k] = -2.0 * p[u][k];
          double bs = 1e300; int bc = 0;
#pragma unroll 4
          for (int m = 0; m < 16; m++) {
            int c = m * 64 + lane;
            const float* cb2 = cbbase + (size_t)c * CD;
            double s = qtab[i * CS + c];
#pragma unroll
            for (int k = 0; k < 8; k++) s = fma((double)cb2[k], pm2[k], s);
            if (s < bs) { bs = s; bc = c; }
          }
#pragma unroll
          for (int o = 32; o; o >>= 1) {
            double obs = __shfl_xor(bs, o, 64);
            int    obc = __shfl_xor(bc, o, 64);
            if (obs < bs || (obs == bs && obc < bc)) { bs = obs; bc = obc; }
          }
          c1[u] = bc;
        }
        // ---- scalars for this row ----
        int rr = 2 * pr + u;
        int cu = __builtin_amdgcn_readfirstlane(c1[u]);
        const float* cbr = cbbase + (size_t)cu * CD;
        double acc = p[u][8];                 // res.b
#pragma unroll
        for (int k = 0; k < 8; k++) acc = fma((double)cbr[k], p[u][k], acc);
        pzv[rr] = acc;
        nt2v[rr] = qtab[i * CS + cu];
        c1i[rr] = cu;
        if (lane == 0)
          out_codes[((size_t)bb * NCB + i) * TT + t0 + w * 4 + rr] = (float)cu;
      }
    }

    // ---- rotation scalars + commit + ns2 recurrence ----
    double Ap[4], Cm[4];
#pragma unroll
    for (int r = 0; r < 4; r++) {
      double pz = pzv[r], nt2 = nt2v[r], n2 = ns2[r];
      double s_ns = sqrt(n2), s_nt = sqrt(nt2);
      double rns = 1.0 / fmax(s_ns, 1e-6), rnt = 1.0 / fmax(s_nt, 1e-6);
      double wn2 = n2 * rns * rns + 2.0 * pz * rns * rnt + nt2 * rnt * rnt;
      double rdwn = 1.0 / fmax(sqrt(wn2), 1e-6);
      double eu = n2 * rns;
      double ew = (n2 * rns + pz * rnt) * rdwn;
      double scale = s_nt * rns;
      double A = scale * (1.0 - 2.0 * ew * rdwn * rns);
      double C = scale * rnt * 2.0 * (eu - ew * rdwn);
      commit += n2 - 2.0 * pz + nt2;
      double ap = 1.0 - A;
      Ap[r] = ap; Cm[r] = C;
      ns2[r] = ap * ap * n2 - 2.0 * ap * C * pz + C * C * nt2;
    }

    // ---- res update: res' = Ap*res - Cm*(b + Wn.cb)  (4 rows batched) ----
    float cbf[4][8];
#pragma unroll
    for (int r = 0; r < 4; r++) {
      const float* cbr = cbbase + (size_t)c1i[r] * CD;
#pragma unroll
      for (int k = 0; k < 8; k++) cbf[r][k] = cbr[k];
    }
#pragma unroll
    for (int j = 0; j < 8; j++) {
      int d = j * 64 + lane;
      double wv[KK];
#pragma unroll
      for (int k = 0; k < KK; k++) wv[k] = wnl[k * DD + d];
#pragma unroll
      for (int r = 0; r < 4; r++) {
        double imp = wv[8];
#pragma unroll
        for (int k = 0; k < 8; k++) imp = fma((double)cbf[r][k], wv[k], imp);
        res[r][j] = Ap[r] * res[r][j] - Cm[r] * imp;
      }
    }
    __syncthreads();   // wnl reads done before next stage overwrites
  }

  if (lane == 0) atomicAdd(accp, commit);

  // ---- z_q = z - res_final : transpose res via LDS, subtract coalesced ----
#pragma unroll
  for (int r = 0; r < 4; r++)
#pragma unroll
    for (int j = 0; j < 8; j++)
      tile[(j * 64 + lane) * 17 + (w * 4 + r)] = (float)res[r][j];
  __syncthreads();
#pragma unroll
  for (int m = 0; m < 8; m++) {
    int F = tid + m * 256, d = F >> 2, qq = F & 3;
    const float4 v = *(const float4*)(zb + (size_t)d * TT + qq * 4);
    float4 o;
    o.x = v.x - tile[d * 17 + qq * 4 + 0];
    o.y = v.y - tile[d * 17 + qq * 4 + 1];
    o.z = v.z - tile[d * 17 + qq * 4 + 2];
    o.w = v.w - tile[d * 17 + qq * 4 + 3];
    *(float4*)(out_zq + ((size_t)bb * DD + d) * TT + t0 + qq * 4) = o;
  }
}

__global__ void k_fin(const double* __restrict__ accp, float* __restrict__ outc) {
  outc[0] = (float)(accp[0] * 1.25 / (double)((size_t)NB * TT * DD));
}

extern "C" void kernel_launch(void* const* d_in, const int* in_sizes, int n_in,
                              void* d_out, int out_size, void* d_ws, size_t ws_size,
                              hipStream_t stream) {
  const float* z  = (const float*)d_in[0];
  const float* V  = (const float*)d_in[1];
  const float* g  = (const float*)d_in[2];
  const float* b  = (const float*)d_in[3];
  const float* CB = (const float*)d_in[4];
  float* out = (float*)d_out;

  double* acc = (double*)d_ws;
  double* wn  = (double*)((char*)d_ws + WS_WN_OFF);
  double* q   = (double*)((char*)d_ws + WS_Q_OFF);
  float*  qf  = (float*)((char*)d_ws + WS_QF_OFF);

  hipMemsetAsync(d_ws, 0, 64, stream);
  hipLaunchKernelGGL(k_wn, dim3((NCB * DD + 255) / 256), dim3(256), 0, stream, V, g, b, wn);
  hipLaunchKernelGGL(k_q, dim3((NCB * CS) / 4), dim3(256), 0, stream, CB, b, wn, q, qf);
  hipLaunchKernelGGL(k_main, dim3(NB * (TT / 16)), dim3(256), 0, stream,
                     z, CB, wn, q, qf,
                     out, out + (size_t)NB * DD * TT, acc);
  hipLaunchKernelGGL(k_fin, dim3(1), dim3(1), 0, stream,
                     acc, out + (size_t)NB * DD * TT + (size_t)NB * NCB * TT);
}

// Round 4
// 924.237 us; speedup vs baseline: 2.0898x; 1.3044x over previous
//
#include <hip/hip_runtime.h>

// ResidualSimVQ eval forward — R4: R3 with the commit-loss 64x bug fixed.
// implicit_c = CB_c @ Wn^T + b (rank 8) => argmin needs only p = res@[Wn|b].
// rot = A*res + C*zq with wave-uniform scalars; res' = (1-A)res - C*zq;
// ns2 by recurrence, nt2 from qtab, pz = pb + cb.p.
// f32 scoring + gap-triggered exact-f64 fallback.
// NOTE: `commit` is accumulated from wave-uniform scalars -> every lane already
// holds the per-wave total. Do NOT wave-reduce it (R3's 64x bug); lane 0's
// copy IS the wave sum.

#define NB  16
#define DD  512
#define TT  2048
#define NCB 9
#define CS  1024
#define CD  8
#define KK  9   // CD + 1: row 8 of the table is the bias b
#define NBLK (NB * (TT / 16))   // 2048 k_main blocks

#define WS_WN_OFF  16384                               // f64 Wn, k-major: [i][k][d]
#define WS_Q_OFF   (WS_WN_OFF + (size_t)NCB*KK*DD*8)   // f64 ||implicit||^2
#define WS_QF_OFF  (WS_Q_OFF  + (size_t)NCB*CS*8)      // f32 copy

__global__ void k_wn(const float* __restrict__ V, const float* __restrict__ g,
                     const float* __restrict__ bp, double* __restrict__ wn) {
  int gid = blockIdx.x * 256 + threadIdx.x;
  if (gid >= NCB * DD) return;
  int i = gid / DD, d = gid % DD;
  const float* vp = V + (size_t)gid * CD;
  double v[CD], s = 0.0;
#pragma unroll
  for (int k = 0; k < CD; k++) { v[k] = (double)vp[k]; s = fma(v[k], v[k], s); }
  double den = fmax(sqrt(s), 1e-12);
  double gg = (double)g[gid];
#pragma unroll
  for (int k = 0; k < CD; k++)
    wn[((size_t)i * KK + k) * DD + d] = gg * v[k] / den;
  wn[((size_t)i * KK + CD) * DD + d] = (double)bp[gid];   // bias row
}

__global__ void k_q(const float* __restrict__ CBp, const float* __restrict__ bp,
                    const double* __restrict__ wn,
                    double* __restrict__ q, float* __restrict__ qf) {
  int wid = blockIdx.x * 4 + (threadIdx.x >> 6);
  int lane = threadIdx.x & 63;
  int i = wid / CS, c = wid % CS;
  const float* cb = CBp + (size_t)(i * CS + c) * CD;
  double cbv[CD];
#pragma unroll
  for (int k = 0; k < CD; k++) cbv[k] = (double)cb[k];
  const double* wnp = wn + (size_t)i * KK * DD;
  const float* bb = bp + (size_t)i * DD;
  double acc = 0.0;
#pragma unroll
  for (int j = 0; j < 8; j++) {
    int d = j * 64 + lane;
    double imp = (double)bb[d];
#pragma unroll
    for (int k = 0; k < CD; k++) imp = fma(cbv[k], wnp[(size_t)k * DD + d], imp);
    acc = fma(imp, imp, acc);
  }
#pragma unroll
  for (int o = 32; o; o >>= 1) acc += __shfl_xor(acc, o, 64);
  if (lane == 0) { q[wid] = acc; qf[wid] = (float)acc; }
}

__launch_bounds__(256, 2)
__global__ void k_main(const float* __restrict__ z, const float* __restrict__ CBp,
                       const double* __restrict__ wn, const double* __restrict__ qtab,
                       const float* __restrict__ qftab,
                       float* __restrict__ out_zq, float* __restrict__ out_codes,
                       double* __restrict__ partials) {
  __shared__ __align__(16) double smem_d[KK * DD];   // 36864 B
  __shared__ double cbuf[4];
  double* wnl = smem_d;
  float*  tile = (float*)smem_d;                     // needs 512*17*4 = 34816 B

  const int tid = threadIdx.x, lane = tid & 63, w = tid >> 6;
  const int bb = blockIdx.x >> 7, tg = blockIdx.x & 127;
  const int t0 = tg * 16;
  const float* zb = z + (size_t)bb * DD * TT + t0;

  // ---- stage z[b, :, t0:t0+16] coalesced (float4 over t), transpose in LDS --
#pragma unroll
  for (int m = 0; m < 8; m++) {
    int F = tid + m * 256, d = F >> 2, qq = F & 3;
    const float4 v = *(const float4*)(zb + (size_t)d * TT + qq * 4);
    tile[d * 17 + qq * 4 + 0] = v.x; tile[d * 17 + qq * 4 + 1] = v.y;
    tile[d * 17 + qq * 4 + 2] = v.z; tile[d * 17 + qq * 4 + 3] = v.w;
  }
  __syncthreads();

  double res[4][8], ns2[4];
#pragma unroll
  for (int r = 0; r < 4; r++) {
    double s = 0.0;
#pragma unroll
    for (int j = 0; j < 8; j++) {
      res[r][j] = (double)tile[(j * 64 + lane) * 17 + (w * 4 + r)];
      s = fma(res[r][j], res[r][j], s);
    }
    ns2[r] = s;
  }
#pragma unroll
  for (int o = 32; o; o >>= 1)
#pragma unroll
    for (int r = 0; r < 4; r++) ns2[r] += __shfl_xor(ns2[r], o, 64);
  __syncthreads();

  double commit = 0.0;

  for (int i = 0; i < NCB; i++) {
    // ---- stage [Wn | b] (f64, k-major) ----
#pragma unroll
    for (int m = 0; m < 18; m++)
      wnl[tid + m * 256] = wn[(size_t)i * (KK * DD) + tid + m * 256];
    __syncthreads();

    const float* cbbase = CBp + (size_t)i * CS * CD;
    const float* qfb = qftab + i * CS;
    int    c1i[4];
    double pzv[4], nt2v[4];

#pragma unroll
    for (int pr = 0; pr < 2; pr++) {
      // ---- phase 1: p[u][k] = res . [Wn|b]  (2 rows interleaved) ----
      double p[2][KK];
#pragma unroll
      for (int u = 0; u < 2; u++)
#pragma unroll
        for (int k = 0; k < KK; k++) p[u][k] = 0.0;
#pragma unroll
      for (int j = 0; j < 8; j++) {
        int d = j * 64 + lane;
        double wv[KK];
#pragma unroll
        for (int k = 0; k < KK; k++) wv[k] = wnl[k * DD + d];
#pragma unroll
        for (int u = 0; u < 2; u++) {
          double rv = res[2 * pr + u][j];
#pragma unroll
          for (int k = 0; k < KK; k++) p[u][k] = fma(rv, wv[k], p[u][k]);
        }
      }
#pragma unroll
      for (int o = 32; o; o >>= 1)
#pragma unroll
        for (int u = 0; u < 2; u++)
#pragma unroll
          for (int k = 0; k < KK; k++) p[u][k] += __shfl_xor(p[u][k], o, 64);

      // ---- phase 2: f32 argmin with top-2 gap tracking (2 rows) ----
      float m2[2][8];
#pragma unroll
      for (int u = 0; u < 2; u++)
#pragma unroll
        for (int k = 0; k < 8; k++) m2[u][k] = (float)(-2.0 * p[u][k]);
      float s1[2] = {3.4e38f, 3.4e38f}, s2[2] = {3.4e38f, 3.4e38f};
      int   c1[2] = {0, 0};
#pragma unroll 4
      for (int m = 0; m < 16; m++) {
        int c = m * 64 + lane;
        const float4 c0 = *(const float4*)(cbbase + (size_t)c * CD);
        const float4 cx = *(const float4*)(cbbase + (size_t)c * CD + 4);
        float qv = qfb[c];
#pragma unroll
        for (int u = 0; u < 2; u++) {
          float s = qv;
          s = fmaf(c0.x, m2[u][0], s); s = fmaf(c0.y, m2[u][1], s);
          s = fmaf(c0.z, m2[u][2], s); s = fmaf(c0.w, m2[u][3], s);
          s = fmaf(cx.x, m2[u][4], s); s = fmaf(cx.y, m2[u][5], s);
          s = fmaf(cx.z, m2[u][6], s); s = fmaf(cx.w, m2[u][7], s);
          if (s < s1[u]) { s2[u] = s1[u]; s1[u] = s; c1[u] = c; }
          else           { s2[u] = fminf(s2[u], s); }
        }
      }
#pragma unroll
      for (int o = 32; o; o >>= 1) {
#pragma unroll
        for (int u = 0; u < 2; u++) {
          float os1 = __shfl_xor(s1[u], o, 64);
          int   oc1 = __shfl_xor(c1[u], o, 64);
          float os2 = __shfl_xor(s2[u], o, 64);
          float hi = fmaxf(s1[u], os1);
          s2[u] = fminf(fminf(s2[u], os2), hi);
          if (os1 < s1[u] || (os1 == s1[u] && oc1 < c1[u])) { s1[u] = os1; c1[u] = oc1; }
        }
      }
#pragma unroll
      for (int u = 0; u < 2; u++) {
        if (s2[u] - s1[u] < 0.03f) {      // wave-uniform, rare: exact f64
          double pm2[8];
#pragma unroll
          for (int k = 0; k < 8; k++) pm2[k] = -2.0 * p[u][k];
          double bs = 1e300; int bc = 0;
#pragma unroll 4
          for (int m = 0; m < 16; m++) {
            int c = m * 64 + lane;
            const float* cb2 = cbbase + (size_t)c * CD;
            double s = qtab[i * CS + c];
#pragma unroll
            for (int k = 0; k < 8; k++) s = fma((double)cb2[k], pm2[k], s);
            if (s < bs) { bs = s; bc = c; }
          }
#pragma unroll
          for (int o = 32; o; o >>= 1) {
            double obs = __shfl_xor(bs, o, 64);
            int    obc = __shfl_xor(bc, o, 64);
            if (obs < bs || (obs == bs && obc < bc)) { bs = obs; bc = obc; }
          }
          c1[u] = bc;
        }
        // ---- scalars for this row ----
        int rr = 2 * pr + u;
        int cu = __builtin_amdgcn_readfirstlane(c1[u]);
        const float* cbr = cbbase + (size_t)cu * CD;
        double acc = p[u][8];                 // res.b
#pragma unroll
        for (int k = 0; k < 8; k++) acc = fma((double)cbr[k], p[u][k], acc);
        pzv[rr] = acc;
        nt2v[rr] = qtab[i * CS + cu];
        c1i[rr] = cu;
        if (lane == 0)
          out_codes[((size_t)bb * NCB + i) * TT + t0 + w * 4 + rr] = (float)cu;
      }
    }

    // ---- rotation scalars + commit + ns2 recurrence (all wave-uniform) ----
    double Ap[4], Cm[4];
#pragma unroll
    for (int r = 0; r < 4; r++) {
      double pz = pzv[r], nt2 = nt2v[r], n2 = ns2[r];
      double s_ns = sqrt(n2), s_nt = sqrt(nt2);
      double rns = 1.0 / fmax(s_ns, 1e-6), rnt = 1.0 / fmax(s_nt, 1e-6);
      double wn2 = n2 * rns * rns + 2.0 * pz * rns * rnt + nt2 * rnt * rnt;
      double rdwn = 1.0 / fmax(sqrt(wn2), 1e-6);
      double eu = n2 * rns;
      double ew = (n2 * rns + pz * rnt) * rdwn;
      double scale = s_nt * rns;
      double A = scale * (1.0 - 2.0 * ew * rdwn * rns);
      double C = scale * rnt * 2.0 * (eu - ew * rdwn);
      commit += n2 - 2.0 * pz + nt2;
      double ap = 1.0 - A;
      Ap[r] = ap; Cm[r] = C;
      ns2[r] = ap * ap * n2 - 2.0 * ap * C * pz + C * C * nt2;
    }

    // ---- res update: res' = Ap*res - Cm*(b + Wn.cb)  (4 rows batched) ----
    float cbf[4][8];
#pragma unroll
    for (int r = 0; r < 4; r++) {
      const float* cbr = cbbase + (size_t)c1i[r] * CD;
#pragma unroll
      for (int k = 0; k < 8; k++) cbf[r][k] = cbr[k];
    }
#pragma unroll
    for (int j = 0; j < 8; j++) {
      int d = j * 64 + lane;
      double wv[KK];
#pragma unroll
      for (int k = 0; k < KK; k++) wv[k] = wnl[k * DD + d];
#pragma unroll
      for (int r = 0; r < 4; r++) {
        double imp = wv[8];
#pragma unroll
        for (int k = 0; k < 8; k++) imp = fma((double)cbf[r][k], wv[k], imp);
        res[r][j] = Ap[r] * res[r][j] - Cm[r] * imp;
      }
    }
    __syncthreads();   // wnl reads done before next stage overwrites
  }

  // ---- commit: wave-uniform already (per-wave total); no reduction! ----
  if (lane == 0) cbuf[w] = commit;

  // ---- z_q = z - res_final : transpose res via LDS, subtract coalesced ----
#pragma unroll
  for (int r = 0; r < 4; r++)
#pragma unroll
    for (int j = 0; j < 8; j++)
      tile[(j * 64 + lane) * 17 + (w * 4 + r)] = (float)res[r][j];
  __syncthreads();   // covers cbuf too
#pragma unroll
  for (int m = 0; m < 8; m++) {
    int F = tid + m * 256, d = F >> 2, qq = F & 3;
    const float4 v = *(const float4*)(zb + (size_t)d * TT + qq * 4);
    float4 o;
    o.x = v.x - tile[d * 17 + qq * 4 + 0];
    o.y = v.y - tile[d * 17 + qq * 4 + 1];
    o.z = v.z - tile[d * 17 + qq * 4 + 2];
    o.w = v.w - tile[d * 17 + qq * 4 + 3];
    *(float4*)(out_zq + ((size_t)bb * DD + d) * TT + t0 + qq * 4) = o;
  }
  if (tid == 0)
    partials[blockIdx.x] = cbuf[0] + cbuf[1] + cbuf[2] + cbuf[3];
}

__global__ void k_fin(const double* __restrict__ partials, float* __restrict__ outc) {
  __shared__ double sb[4];
  int tid = threadIdx.x, lane = tid & 63, w = tid >> 6;
  double s = 0.0;
#pragma unroll
  for (int m = 0; m < NBLK / 256; m++) s += partials[tid + m * 256];
#pragma unroll
  for (int o = 32; o; o >>= 1) s += __shfl_xor(s, o, 64);
  if (lane == 0) sb[w] = s;
  __syncthreads();
  if (tid == 0) {
    double tot = sb[0] + sb[1] + sb[2] + sb[3];
    outc[0] = (float)(tot * 1.25 / (double)((size_t)NB * TT * DD));
  }
}

extern "C" void kernel_launch(void* const* d_in, const int* in_sizes, int n_in,
                              void* d_out, int out_size, void* d_ws, size_t ws_size,
                              hipStream_t stream) {
  const float* z  = (const float*)d_in[0];
  const float* V  = (const float*)d_in[1];
  const float* g  = (const float*)d_in[2];
  const float* b  = (const float*)d_in[3];
  const float* CB = (const float*)d_in[4];
  float* out = (float*)d_out;

  double* parts = (double*)d_ws;
  double* wn  = (double*)((char*)d_ws + WS_WN_OFF);
  double* q   = (double*)((char*)d_ws + WS_Q_OFF);
  float*  qf  = (float*)((char*)d_ws + WS_QF_OFF);

  hipLaunchKernelGGL(k_wn, dim3((NCB * DD + 255) / 256), dim3(256), 0, stream, V, g, b, wn);
  hipLaunchKernelGGL(k_q, dim3((NCB * CS) / 4), dim3(256), 0, stream, CB, b, wn, q, qf);
  hipLaunchKernelGGL(k_main, dim3(NBLK), dim3(256), 0, stream,
                     z, CB, wn, q, qf,
                     out, out + (size_t)NB * DD * TT, parts);
  hipLaunchKernelGGL(k_fin, dim3(1), dim3(256), 0, stream,
                     parts, out + (size_t)NB * DD * TT + (size_t)NB * NCB * TT);
}